// Round 1
// baseline (1047.598 us; speedup 1.0000x reference)
//
#include <hip/hip_runtime.h>

#define NN 50000
#define NE 400000
#define NBATCH 16
#define DH 128
#define DE 64
#define DHID 256

// ---- monotone float<->uint encoding for atomicMax on signed floats ----
__device__ __forceinline__ unsigned enc_f(float f) {
  unsigned u = __float_as_uint(f);
  return (u & 0x80000000u) ? ~u : (u | 0x80000000u);
}
__device__ __forceinline__ float dec_f(unsigned x) {
  unsigned u = (x & 0x80000000u) ? (x ^ 0x80000000u) : ~x;
  return __uint_as_float(u);
}

__global__ void init_seg(unsigned* __restrict__ segmax, float* __restrict__ segsum) {
  int i = blockIdx.x * 256 + threadIdx.x;
  if (i < NN) { segmax[i] = 0u; segsum[i] = 0.0f; }
}

// Zq[b][c] = b1g[c] + sum_k q[b,k] * W1g[256+k][c]   (bias folded in)
__global__ void zq_kernel(const float* __restrict__ q, const float* __restrict__ W1g,
                          const float* __restrict__ b1g, float* __restrict__ Zq) {
  int b = blockIdx.x, c = threadIdx.x;
  float acc = b1g[c];
#pragma unroll 4
  for (int k = 0; k < DH; ++k)
    acc = fmaf(q[b * DH + k], W1g[(2 * DH + k) * DHID + c], acc);
  Zq[b * DHID + c] = acc;
}

// P[n][nt*256 + c]:
//   nt=0: h@W1g[0:128]   (gate-src)    nt=1: h@W1s[0:128]   (score-src)
//   nt=2: h@W1g[128:256] (gate-dst)    nt=3: h@W1s[128:256] (score-dst)
__global__ __launch_bounds__(256)
void node_gemm(const float* __restrict__ h, const float* __restrict__ W1g,
               const float* __restrict__ W1s, float* __restrict__ P) {
  __shared__ float hs[64][128];   // [row][k]  32KB
  __shared__ float Bs[16][256];   // [k][col]  16KB chunk
  const int tid = threadIdx.x;
  const int mt = blockIdx.x, nt = blockIdx.y;
  const int n0 = mt * 64;
  const float* Wsec = (nt == 0) ? W1g
                    : (nt == 1) ? W1s
                    : (nt == 2) ? (W1g + DH * DHID)
                                : (W1s + DH * DHID);
  // load h tile (rows n0..n0+63, all K=128), zero-pad tail rows
  {
    int r = tid >> 5;
    int k4 = (tid & 31) * 4;
#pragma unroll
    for (int p = 0; p < 8; ++p) {
      int rr = p * 8 + r;
      int n = n0 + rr;
      float4 v = make_float4(0.f, 0.f, 0.f, 0.f);
      if (n < NN) v = *(const float4*)&h[n * DH + k4];
      *(float4*)&hs[rr][k4] = v;
    }
  }
  const int cx = tid & 31;   // col group: cols {4cx..4cx+3, 128+4cx..+3}
  const int ry = tid >> 5;   // row group: rows ry*8..+7
  const int r0 = ry * 8;
  float acc[8][8];
#pragma unroll
  for (int i = 0; i < 8; ++i)
#pragma unroll
    for (int j = 0; j < 8; ++j) acc[i][j] = 0.f;

  for (int kc = 0; kc < 8; ++kc) {
    __syncthreads();
    {
      int kk = tid >> 6;
      int cf = (tid & 63) * 4;
#pragma unroll
      for (int p = 0; p < 4; ++p)
        *(float4*)&Bs[p * 4 + kk][cf] =
            *(const float4*)&Wsec[(kc * 16 + p * 4 + kk) * DHID + cf];
    }
    __syncthreads();
    for (int k4 = 0; k4 < 16; k4 += 4) {
      float4 av[8];
#pragma unroll
      for (int i = 0; i < 8; ++i)
        av[i] = *(const float4*)&hs[r0 + i][kc * 16 + k4];
#pragma unroll
      for (int kk = 0; kk < 4; ++kk) {
        float4 blo = *(const float4*)&Bs[k4 + kk][cx * 4];
        float4 bhi = *(const float4*)&Bs[k4 + kk][128 + cx * 4];
        float b[8] = {blo.x, blo.y, blo.z, blo.w, bhi.x, bhi.y, bhi.z, bhi.w};
#pragma unroll
        for (int i = 0; i < 8; ++i) {
          const float* ap = (const float*)&av[i];
          float a = ap[kk];
#pragma unroll
          for (int j = 0; j < 8; ++j) acc[i][j] = fmaf(a, b[j], acc[i][j]);
        }
      }
    }
  }
#pragma unroll
  for (int i = 0; i < 8; ++i) {
    int n = n0 + r0 + i;
    if (n < NN) {
      float4 lo = make_float4(acc[i][0], acc[i][1], acc[i][2], acc[i][3]);
      float4 hi = make_float4(acc[i][4], acc[i][5], acc[i][6], acc[i][7]);
      *(float4*)&P[n * 1024 + nt * 256 + cx * 4] = lo;
      *(float4*)&P[n * 1024 + nt * 256 + 128 + cx * 4] = hi;
    }
  }
}

// Fused edge kernel: se = e@W1s[256:320] (tiled GEMM, 64 edges/block) +
// gathers of node projections + both MLP heads + raw score + segment max.
__global__ __launch_bounds__(256)
void edge_kernel(const float* __restrict__ eattr, const int* __restrict__ eidx,
                 const int* __restrict__ ebat,
                 const float* __restrict__ W1s, const float* __restrict__ b1s,
                 const float* __restrict__ W2g, const float* __restrict__ b2g,
                 const float* __restrict__ W2s, const float* __restrict__ b2s,
                 const float* __restrict__ P, const float* __restrict__ Zq,
                 float* __restrict__ raw, unsigned* __restrict__ segmax) {
  __shared__ float es[64][68];     // [edge][k] padded  17.4KB
  __shared__ float Wc[16][256];    // W1s e-section K-chunk  16KB
  __shared__ float w2g_s[256], w2s_s[256], b1s_s[256];
  __shared__ int src_s[64], dst_s[64], bat_s[64];
  const int tid = threadIdx.x;
  const int e0 = blockIdx.x * 64;

  {
    int er = tid >> 4;           // +16 per pass
    int k4 = (tid & 15) * 4;
#pragma unroll
    for (int p = 0; p < 4; ++p) {
      int ee = p * 16 + er;
      *(float4*)&es[ee][k4] = *(const float4*)&eattr[(e0 + ee) * DE + k4];
    }
  }
  if (tid < 256) {
    w2g_s[tid] = W2g[tid];
    w2s_s[tid] = W2s[tid];
    b1s_s[tid] = b1s[tid];
  }
  if (tid < 64) {
    src_s[tid] = eidx[e0 + tid];
    dst_s[tid] = eidx[NE + e0 + tid];
    bat_s[tid] = ebat[e0 + tid];
  }

  const int cx = tid & 31;
  const int ry = tid >> 5;       // 0..7 -> 8 edges each
  const int r0 = ry * 8;
  float acc[8][8];
#pragma unroll
  for (int i = 0; i < 8; ++i)
#pragma unroll
    for (int j = 0; j < 8; ++j) acc[i][j] = 0.f;

  for (int kc = 0; kc < 4; ++kc) {
    __syncthreads();
    {
      int kk = tid >> 6;
      int cf = (tid & 63) * 4;
#pragma unroll
      for (int p = 0; p < 4; ++p)
        *(float4*)&Wc[p * 4 + kk][cf] =
            *(const float4*)&W1s[(2 * DH + kc * 16 + p * 4 + kk) * DHID + cf];
    }
    __syncthreads();
    for (int k4 = 0; k4 < 16; k4 += 4) {
      float4 av[8];
#pragma unroll
      for (int i = 0; i < 8; ++i)
        av[i] = *(const float4*)&es[r0 + i][kc * 16 + k4];
#pragma unroll
      for (int kk = 0; kk < 4; ++kk) {
        float4 blo = *(const float4*)&Wc[k4 + kk][cx * 4];
        float4 bhi = *(const float4*)&Wc[k4 + kk][128 + cx * 4];
        float b[8] = {blo.x, blo.y, blo.z, blo.w, bhi.x, bhi.y, bhi.z, bhi.w};
#pragma unroll
        for (int i = 0; i < 8; ++i) {
          const float* ap = (const float*)&av[i];
          float a = ap[kk];
#pragma unroll
          for (int j = 0; j < 8; ++j) acc[i][j] = fmaf(a, b[j], acc[i][j]);
        }
      }
    }
  }

  // ---- epilogue: per edge, gather node/graph projections, both heads ----
  const float4* P4 = (const float4*)P;    // P row = 256 float4
  const float4* Zq4 = (const float4*)Zq;  // Zq row = 64 float4
  const float b2gv = b2g[0], b2sv = b2s[0];
  const float4 w2g_lo = *(const float4*)&w2g_s[cx * 4];
  const float4 w2g_hi = *(const float4*)&w2g_s[128 + cx * 4];
  const float4 w2s_lo = *(const float4*)&w2s_s[cx * 4];
  const float4 w2s_hi = *(const float4*)&w2s_s[128 + cx * 4];
  const float4 b1_lo = *(const float4*)&b1s_s[cx * 4];
  const float4 b1_hi = *(const float4*)&b1s_s[128 + cx * 4];

#pragma unroll 2
  for (int j = 0; j < 8; ++j) {
    int er = r0 + j;
    int s = src_s[er], d = dst_s[er], b = bat_s[er];
    int sb = s * 256, db = d * 256;
    float4 gs_lo = P4[sb + cx],       gs_hi = P4[sb + 32 + cx];
    float4 ss_lo = P4[sb + 64 + cx],  ss_hi = P4[sb + 96 + cx];
    float4 gd_lo = P4[db + 128 + cx], gd_hi = P4[db + 160 + cx];
    float4 sd_lo = P4[db + 192 + cx], sd_hi = P4[db + 224 + cx];
    float4 zq_lo = Zq4[b * 64 + cx],  zq_hi = Zq4[b * 64 + 32 + cx];

    float gp =
        fmaxf(gs_lo.x + gd_lo.x + zq_lo.x, 0.f) * w2g_lo.x
      + fmaxf(gs_lo.y + gd_lo.y + zq_lo.y, 0.f) * w2g_lo.y
      + fmaxf(gs_lo.z + gd_lo.z + zq_lo.z, 0.f) * w2g_lo.z
      + fmaxf(gs_lo.w + gd_lo.w + zq_lo.w, 0.f) * w2g_lo.w
      + fmaxf(gs_hi.x + gd_hi.x + zq_hi.x, 0.f) * w2g_hi.x
      + fmaxf(gs_hi.y + gd_hi.y + zq_hi.y, 0.f) * w2g_hi.y
      + fmaxf(gs_hi.z + gd_hi.z + zq_hi.z, 0.f) * w2g_hi.z
      + fmaxf(gs_hi.w + gd_hi.w + zq_hi.w, 0.f) * w2g_hi.w;

    float sp =
        fmaxf(acc[j][0] + ss_lo.x + sd_lo.x + b1_lo.x, 0.f) * w2s_lo.x
      + fmaxf(acc[j][1] + ss_lo.y + sd_lo.y + b1_lo.y, 0.f) * w2s_lo.y
      + fmaxf(acc[j][2] + ss_lo.z + sd_lo.z + b1_lo.z, 0.f) * w2s_lo.z
      + fmaxf(acc[j][3] + ss_lo.w + sd_lo.w + b1_lo.w, 0.f) * w2s_lo.w
      + fmaxf(acc[j][4] + ss_hi.x + sd_hi.x + b1_hi.x, 0.f) * w2s_hi.x
      + fmaxf(acc[j][5] + ss_hi.y + sd_hi.y + b1_hi.y, 0.f) * w2s_hi.y
      + fmaxf(acc[j][6] + ss_hi.z + sd_hi.z + b1_hi.z, 0.f) * w2s_hi.z
      + fmaxf(acc[j][7] + ss_hi.w + sd_hi.w + b1_hi.w, 0.f) * w2s_hi.w;

#pragma unroll
    for (int m = 16; m >= 1; m >>= 1) {
      gp += __shfl_xor(gp, m);
      sp += __shfl_xor(sp, m);
    }
    if (cx == 0) {
      float gate = 1.f / (1.f + __expf(-(gp + b2gv)));
      float score = sp + b2sv;
      float rv = gate * score;
      raw[e0 + er] = rv;
      atomicMax(&segmax[d], enc_f(rv));
    }
  }
}

__global__ void exp_pass(const float* __restrict__ raw, const int* __restrict__ dstp,
                         const unsigned* __restrict__ segmax, float* __restrict__ out,
                         float* __restrict__ segsum) {
  int i = blockIdx.x * 256 + threadIdx.x;
  if (i < NE) {
    int d = dstp[i];
    float ex = __expf(raw[i] - dec_f(segmax[d]));
    out[i] = ex;
    atomicAdd(&segsum[d], ex);
  }
}

__global__ void norm_pass(float* __restrict__ out, const int* __restrict__ dstp,
                          const float* __restrict__ segsum) {
  int i = blockIdx.x * 256 + threadIdx.x;
  if (i < NE) out[i] = out[i] / fmaxf(segsum[dstp[i]], 1e-9f);
}

extern "C" void kernel_launch(void* const* d_in, const int* in_sizes, int n_in,
                              void* d_out, int out_size, void* d_ws, size_t ws_size,
                              hipStream_t stream) {
  const float* h   = (const float*)d_in[0];
  const float* e   = (const float*)d_in[1];
  const float* q   = (const float*)d_in[2];
  const int* eidx  = (const int*)d_in[3];
  const int* ebat  = (const int*)d_in[4];
  const float* W1g = (const float*)d_in[5];
  const float* b1g = (const float*)d_in[6];
  const float* W2g = (const float*)d_in[7];
  const float* b2g = (const float*)d_in[8];
  const float* W1s = (const float*)d_in[9];
  const float* b1s = (const float*)d_in[10];
  const float* W2s = (const float*)d_in[11];
  const float* b2s = (const float*)d_in[12];
  float* out = (float*)d_out;

  // workspace carve (207 MB): P | Zq | raw | segmax | segsum
  float* P = (float*)d_ws;
  float* Zq = P + (size_t)NN * 1024;
  float* raw = Zq + NBATCH * DHID;
  unsigned* segmax = (unsigned*)(raw + NE);
  float* segsum = (float*)(segmax + NN);

  hipLaunchKernelGGL(init_seg, dim3(196), dim3(256), 0, stream, segmax, segsum);
  hipLaunchKernelGGL(zq_kernel, dim3(NBATCH), dim3(256), 0, stream, q, W1g, b1g, Zq);
  hipLaunchKernelGGL(node_gemm, dim3(782, 4), dim3(256), 0, stream, h, W1g, W1s, P);
  hipLaunchKernelGGL(edge_kernel, dim3(NE / 64), dim3(256), 0, stream,
                     e, eidx, ebat, W1s, b1s, W2g, b2g, W2s, b2s, P, Zq, raw, segmax);
  hipLaunchKernelGGL(exp_pass, dim3(1563), dim3(256), 0, stream,
                     raw, eidx + NE, segmax, out, segsum);
  hipLaunchKernelGGL(norm_pass, dim3(1563), dim3(256), 0, stream,
                     out, eidx + NE, segsum);
}

// Round 2
// 633.082 us; speedup vs baseline: 1.6548x; 1.6548x over previous
//
#include <hip/hip_runtime.h>

#define NN 50000
#define NE 400000
#define NBATCH 16
#define DH 128
#define DE 64
#define DHID 256

// ---- monotone float<->uint encoding for atomicMax on signed floats ----
__device__ __forceinline__ unsigned enc_f(float f) {
  unsigned u = __float_as_uint(f);
  return (u & 0x80000000u) ? ~u : (u | 0x80000000u);
}
__device__ __forceinline__ float dec_f(unsigned x) {
  unsigned u = (x & 0x80000000u) ? (x ^ 0x80000000u) : ~x;
  return __uint_as_float(u);
}
// fp32 -> bf16 (round-to-nearest-even), returned in low 16 bits
__device__ __forceinline__ unsigned f2bf(float x) {
  unsigned u = __float_as_uint(x);
  return (u + 0x7fffu + ((u >> 16) & 1u)) >> 16;
}
// unpack 8 bf16 (uint4) -> 8 fp32
__device__ __forceinline__ void bf8_unpack(uint4 v, float* f) {
  f[0] = __uint_as_float(v.x << 16); f[1] = __uint_as_float(v.x & 0xffff0000u);
  f[2] = __uint_as_float(v.y << 16); f[3] = __uint_as_float(v.y & 0xffff0000u);
  f[4] = __uint_as_float(v.z << 16); f[5] = __uint_as_float(v.z & 0xffff0000u);
  f[6] = __uint_as_float(v.w << 16); f[7] = __uint_as_float(v.w & 0xffff0000u);
}

__global__ void init_seg(unsigned* __restrict__ segmax, float* __restrict__ segsum) {
  int i = blockIdx.x * 256 + threadIdx.x;
  if (i < NN) { segmax[i] = 0u; segsum[i] = 0.0f; }
}

// Zq[b][c] = b1g[c] + q[b] @ W1g[256:384]  (bias folded; fp32, tiny -> L1/L2 resident)
__global__ void zq_kernel(const float* __restrict__ q, const float* __restrict__ W1g,
                          const float* __restrict__ b1g, float* __restrict__ Zq) {
  int b = blockIdx.x, c = threadIdx.x;
  float acc = b1g[c];
#pragma unroll 4
  for (int k = 0; k < DH; ++k)
    acc = fmaf(q[b * DH + k], W1g[(2 * DH + k) * DHID + c], acc);
  Zq[b * DHID + c] = acc;
}

// P (bf16), per node 1024 values, lane-permuted within each 256-block:
//   block nt, lane cx (0..31) owns cols {4cx..4cx+3, 128+4cx..131+4cx} stored
//   contiguously as 8 bf16 = 16B at element offset n*1024 + nt*256 + cx*8.
//   nt=0: h@W1g[0:128] (gate-src)   nt=1: h@W1s[0:128]   (score-src)
//   nt=2: h@W1g[128:256] (gate-dst) nt=3: h@W1s[128:256] (score-dst)
__global__ __launch_bounds__(256)
void node_gemm(const float* __restrict__ h, const float* __restrict__ W1g,
               const float* __restrict__ W1s, unsigned short* __restrict__ P) {
  __shared__ float hs[64][128];   // 32KB
  __shared__ float Bs[16][256];   // 16KB
  const int tid = threadIdx.x;
  const int mt = blockIdx.x, nt = blockIdx.y;
  const int n0 = mt * 64;
  const float* Wsec = (nt == 0) ? W1g
                    : (nt == 1) ? W1s
                    : (nt == 2) ? (W1g + DH * DHID)
                                : (W1s + DH * DHID);
  {
    int r = tid >> 5;
    int k4 = (tid & 31) * 4;
#pragma unroll
    for (int p = 0; p < 8; ++p) {
      int rr = p * 8 + r;
      int n = n0 + rr;
      float4 v = make_float4(0.f, 0.f, 0.f, 0.f);
      if (n < NN) v = *(const float4*)&h[n * DH + k4];
      *(float4*)&hs[rr][k4] = v;
    }
  }
  const int cx = tid & 31;
  const int ry = tid >> 5;
  const int r0 = ry * 8;
  float acc[8][8];
#pragma unroll
  for (int i = 0; i < 8; ++i)
#pragma unroll
    for (int j = 0; j < 8; ++j) acc[i][j] = 0.f;

  for (int kc = 0; kc < 8; ++kc) {
    __syncthreads();
    {
      int kk = tid >> 6;
      int cf = (tid & 63) * 4;
#pragma unroll
      for (int p = 0; p < 4; ++p)
        *(float4*)&Bs[p * 4 + kk][cf] =
            *(const float4*)&Wsec[(kc * 16 + p * 4 + kk) * DHID + cf];
    }
    __syncthreads();
    for (int k4 = 0; k4 < 16; k4 += 4) {
      float4 av[8];
#pragma unroll
      for (int i = 0; i < 8; ++i)
        av[i] = *(const float4*)&hs[r0 + i][kc * 16 + k4];
#pragma unroll
      for (int kk = 0; kk < 4; ++kk) {
        float4 blo = *(const float4*)&Bs[k4 + kk][cx * 4];
        float4 bhi = *(const float4*)&Bs[k4 + kk][128 + cx * 4];
        float b[8] = {blo.x, blo.y, blo.z, blo.w, bhi.x, bhi.y, bhi.z, bhi.w};
#pragma unroll
        for (int i = 0; i < 8; ++i) {
          const float* ap = (const float*)&av[i];
          float a = ap[kk];
#pragma unroll
          for (int j = 0; j < 8; ++j) acc[i][j] = fmaf(a, b[j], acc[i][j]);
        }
      }
    }
  }
#pragma unroll
  for (int i = 0; i < 8; ++i) {
    int n = n0 + r0 + i;
    if (n < NN) {
      uint4 st;
      st.x = f2bf(acc[i][0]) | (f2bf(acc[i][1]) << 16);
      st.y = f2bf(acc[i][2]) | (f2bf(acc[i][3]) << 16);
      st.z = f2bf(acc[i][4]) | (f2bf(acc[i][5]) << 16);
      st.w = f2bf(acc[i][6]) | (f2bf(acc[i][7]) << 16);
      *(uint4*)&P[(size_t)n * 1024 + nt * 256 + cx * 8] = st;
    }
  }
}

// Fused edge kernel: se = e@W1s[256:320] (fp32 tile GEMM, 64 edges/block) +
// bf16 gathers of node projections + both MLP heads + raw score + segment max.
__global__ __launch_bounds__(256)
void edge_kernel(const float* __restrict__ eattr, const int* __restrict__ eidx,
                 const int* __restrict__ ebat,
                 const float* __restrict__ W1s, const float* __restrict__ b1s,
                 const float* __restrict__ W2g, const float* __restrict__ b2g,
                 const float* __restrict__ W2s, const float* __restrict__ b2s,
                 const unsigned short* __restrict__ P, const float* __restrict__ Zq,
                 float* __restrict__ raw, unsigned* __restrict__ segmax) {
  __shared__ float es[64][64];     // 16KB (GEMM reads are broadcast; no pad needed)
  __shared__ float Wc[8][256];     // 8KB K-chunk of W1s e-section
  __shared__ float w2g_s[256], w2s_s[256], b1s_s[256];
  __shared__ int src_s[64], dst_s[64], bat_s[64];
  const int tid = threadIdx.x;
  const int e0 = blockIdx.x * 64;

  {
    int er = tid >> 4;
    int k4 = (tid & 15) * 4;
#pragma unroll
    for (int p = 0; p < 4; ++p) {
      int ee = p * 16 + er;
      *(float4*)&es[ee][k4] = *(const float4*)&eattr[(e0 + ee) * DE + k4];
    }
  }
  w2g_s[tid] = W2g[tid];
  w2s_s[tid] = W2s[tid];
  b1s_s[tid] = b1s[tid];
  if (tid < 64) {
    src_s[tid] = eidx[e0 + tid];
    dst_s[tid] = eidx[NE + e0 + tid];
    bat_s[tid] = ebat[e0 + tid];
  }

  const int cx = tid & 31;
  const int ry = tid >> 5;
  const int r0 = ry * 8;
  float acc[8][8];
#pragma unroll
  for (int i = 0; i < 8; ++i)
#pragma unroll
    for (int j = 0; j < 8; ++j) acc[i][j] = 0.f;

  for (int kc = 0; kc < 8; ++kc) {
    __syncthreads();
    {
      int kk = tid >> 5;           // 0..7
      int cf = (tid & 31) * 8;     // 0..248
      const float* wr = &W1s[(2 * DH + kc * 8 + kk) * DHID + cf];
      *(float4*)&Wc[kk][cf] = *(const float4*)wr;
      *(float4*)&Wc[kk][cf + 4] = *(const float4*)(wr + 4);
    }
    __syncthreads();
    for (int k4 = 0; k4 < 8; k4 += 4) {
      float4 av[8];
#pragma unroll
      for (int i = 0; i < 8; ++i)
        av[i] = *(const float4*)&es[r0 + i][kc * 8 + k4];
#pragma unroll
      for (int kk = 0; kk < 4; ++kk) {
        float4 blo = *(const float4*)&Wc[k4 + kk][cx * 4];
        float4 bhi = *(const float4*)&Wc[k4 + kk][128 + cx * 4];
        float b[8] = {blo.x, blo.y, blo.z, blo.w, bhi.x, bhi.y, bhi.z, bhi.w};
#pragma unroll
        for (int i = 0; i < 8; ++i) {
          const float* ap = (const float*)&av[i];
          float a = ap[kk];
#pragma unroll
          for (int j = 0; j < 8; ++j) acc[i][j] = fmaf(a, b[j], acc[i][j]);
        }
      }
    }
  }

  // ---- epilogue: software-pipelined bf16 gathers + both heads ----
  const uint4* Pq = (const uint4*)P;      // node row = 128 uint4 (2KB)
  const float4* Zq4 = (const float4*)Zq;  // Zq row = 64 float4
  const float b2gv = b2g[0], b2sv = b2s[0];
  const float4 w2g_lo = *(const float4*)&w2g_s[cx * 4];
  const float4 w2g_hi = *(const float4*)&w2g_s[128 + cx * 4];
  const float4 w2s_lo = *(const float4*)&w2s_s[cx * 4];
  const float4 w2s_hi = *(const float4*)&w2s_s[128 + cx * 4];
  const float4 b1_lo = *(const float4*)&b1s_s[cx * 4];
  const float4 b1_hi = *(const float4*)&b1s_s[128 + cx * 4];
  const float wg[8] = {w2g_lo.x, w2g_lo.y, w2g_lo.z, w2g_lo.w,
                       w2g_hi.x, w2g_hi.y, w2g_hi.z, w2g_hi.w};
  const float ws[8] = {w2s_lo.x, w2s_lo.y, w2s_lo.z, w2s_lo.w,
                       w2s_hi.x, w2s_hi.y, w2s_hi.z, w2s_hi.w};
  const float b1v[8] = {b1_lo.x, b1_lo.y, b1_lo.z, b1_lo.w,
                        b1_hi.x, b1_hi.y, b1_hi.z, b1_hi.w};

  // prefetch edge r0
  int s_n = src_s[r0], d_n = dst_s[r0], b_n = bat_s[r0];
  uint4 gs_n = Pq[(size_t)s_n * 128 + cx];
  uint4 ss_n = Pq[(size_t)s_n * 128 + 32 + cx];
  uint4 gd_n = Pq[(size_t)d_n * 128 + 64 + cx];
  uint4 sd_n = Pq[(size_t)d_n * 128 + 96 + cx];
  float4 zlo_n = Zq4[b_n * 64 + cx];
  float4 zhi_n = Zq4[b_n * 64 + 32 + cx];

  for (int j = 0; j < 8; ++j) {
    const int dcur = d_n;
    uint4 gs = gs_n, ss = ss_n, gd = gd_n, sd = sd_n;
    float4 zlo = zlo_n, zhi = zhi_n;
    if (j < 7) {
      s_n = src_s[r0 + j + 1]; d_n = dst_s[r0 + j + 1]; b_n = bat_s[r0 + j + 1];
      gs_n = Pq[(size_t)s_n * 128 + cx];
      ss_n = Pq[(size_t)s_n * 128 + 32 + cx];
      gd_n = Pq[(size_t)d_n * 128 + 64 + cx];
      sd_n = Pq[(size_t)d_n * 128 + 96 + cx];
      zlo_n = Zq4[b_n * 64 + cx];
      zhi_n = Zq4[b_n * 64 + 32 + cx];
    }
    float gsf[8], gdf[8], ssf[8], sdf[8];
    bf8_unpack(gs, gsf); bf8_unpack(gd, gdf);
    bf8_unpack(ss, ssf); bf8_unpack(sd, sdf);
    const float zq[8] = {zlo.x, zlo.y, zlo.z, zlo.w, zhi.x, zhi.y, zhi.z, zhi.w};

    float gp = 0.f, sp = 0.f;
#pragma unroll
    for (int t = 0; t < 8; ++t) {
      gp = fmaf(fmaxf(gsf[t] + gdf[t] + zq[t], 0.f), wg[t], gp);
      sp = fmaf(fmaxf(acc[j][t] + ssf[t] + sdf[t] + b1v[t], 0.f), ws[t], sp);
    }
#pragma unroll
    for (int m = 16; m >= 1; m >>= 1) {
      gp += __shfl_xor(gp, m);
      sp += __shfl_xor(sp, m);
    }
    if (cx == 0) {
      float gate = 1.f / (1.f + __expf(-(gp + b2gv)));
      float score = sp + b2sv;
      float rv = gate * score;
      raw[e0 + r0 + j] = rv;
      atomicMax(&segmax[dcur], enc_f(rv));
    }
  }
}

__global__ void exp_pass(const float* __restrict__ raw, const int* __restrict__ dstp,
                         const unsigned* __restrict__ segmax, float* __restrict__ out,
                         float* __restrict__ segsum) {
  int i = blockIdx.x * 256 + threadIdx.x;
  if (i < NE) {
    int d = dstp[i];
    float ex = __expf(raw[i] - dec_f(segmax[d]));
    out[i] = ex;
    atomicAdd(&segsum[d], ex);
  }
}

__global__ void norm_pass(float* __restrict__ out, const int* __restrict__ dstp,
                          const float* __restrict__ segsum) {
  int i = blockIdx.x * 256 + threadIdx.x;
  if (i < NE) out[i] = out[i] / fmaxf(segsum[dstp[i]], 1e-9f);
}

extern "C" void kernel_launch(void* const* d_in, const int* in_sizes, int n_in,
                              void* d_out, int out_size, void* d_ws, size_t ws_size,
                              hipStream_t stream) {
  const float* h   = (const float*)d_in[0];
  const float* e   = (const float*)d_in[1];
  const float* q   = (const float*)d_in[2];
  const int* eidx  = (const int*)d_in[3];
  const int* ebat  = (const int*)d_in[4];
  const float* W1g = (const float*)d_in[5];
  const float* b1g = (const float*)d_in[6];
  const float* W2g = (const float*)d_in[7];
  const float* b2g = (const float*)d_in[8];
  const float* W1s = (const float*)d_in[9];
  const float* b1s = (const float*)d_in[10];
  const float* W2s = (const float*)d_in[11];
  const float* b2s = (const float*)d_in[12];
  float* out = (float*)d_out;

  // workspace carve: P(bf16 102.4MB) | Zq | raw | segmax | segsum
  unsigned short* P = (unsigned short*)d_ws;
  float* Zq = (float*)(P + (size_t)NN * 1024);
  float* raw = Zq + NBATCH * DHID;
  unsigned* segmax = (unsigned*)(raw + NE);
  float* segsum = (float*)(segmax + NN);

  hipLaunchKernelGGL(init_seg, dim3(196), dim3(256), 0, stream, segmax, segsum);
  hipLaunchKernelGGL(zq_kernel, dim3(NBATCH), dim3(256), 0, stream, q, W1g, b1g, Zq);
  hipLaunchKernelGGL(node_gemm, dim3(782, 4), dim3(256), 0, stream, h, W1g, W1s, P);
  hipLaunchKernelGGL(edge_kernel, dim3(NE / 64), dim3(256), 0, stream,
                     e, eidx, ebat, W1s, b1s, W2g, b2g, W2s, b2s, P, Zq, raw, segmax);
  hipLaunchKernelGGL(exp_pass, dim3(1563), dim3(256), 0, stream,
                     raw, eidx + NE, segmax, out, segsum);
  hipLaunchKernelGGL(norm_pass, dim3(1563), dim3(256), 0, stream,
                     out, eidx + NE, segsum);
}

// Round 3
// 546.283 us; speedup vs baseline: 1.9177x; 1.1589x over previous
//
#include <hip/hip_runtime.h>

#define NN 50000
#define NE 400000
#define NBATCH 16
#define DH 128
#define DE 64
#define DHID 256

typedef __attribute__((ext_vector_type(8))) short bf16x8;
typedef __attribute__((ext_vector_type(4))) float f32x4;

// ---- monotone float<->uint encoding for atomicMax on signed floats ----
__device__ __forceinline__ unsigned enc_f(float f) {
  unsigned u = __float_as_uint(f);
  return (u & 0x80000000u) ? ~u : (u | 0x80000000u);
}
__device__ __forceinline__ float dec_f(unsigned x) {
  unsigned u = (x & 0x80000000u) ? (x ^ 0x80000000u) : ~x;
  return __uint_as_float(u);
}
// fp32 -> bf16 (round-to-nearest-even), low 16 bits
__device__ __forceinline__ unsigned f2bf(float x) {
  unsigned u = __float_as_uint(x);
  return (u + 0x7fffu + ((u >> 16) & 1u)) >> 16;
}
__device__ __forceinline__ void bf8_unpack(uint4 v, float* f) {
  f[0] = __uint_as_float(v.x << 16); f[1] = __uint_as_float(v.x & 0xffff0000u);
  f[2] = __uint_as_float(v.y << 16); f[3] = __uint_as_float(v.y & 0xffff0000u);
  f[4] = __uint_as_float(v.z << 16); f[5] = __uint_as_float(v.z & 0xffff0000u);
  f[6] = __uint_as_float(v.w << 16); f[7] = __uint_as_float(v.w & 0xffff0000u);
}

__global__ void init_seg(unsigned* __restrict__ segmax, float* __restrict__ segsum) {
  int i = blockIdx.x * 256 + threadIdx.x;
  if (i < NN) { segmax[i] = 0u; segsum[i] = 0.0f; }
}

// Wb[sec][n=256][k=128] bf16: sec0=W1g[0:128] (gate-src), sec1=W1s[0:128]
// (score-src), sec2=W1g[128:256] (gate-dst), sec3=W1s[128:256] (score-dst).
__global__ void w2bf(const float* __restrict__ W1g, const float* __restrict__ W1s,
                     unsigned short* __restrict__ Wb) {
  int idx = blockIdx.x * 256 + threadIdx.x;   // 131072 total
  int sec = idx >> 15;
  int rem = idx & 32767;
  int n = rem >> 7;
  int k = rem & 127;
  const float* W = (sec & 1) ? W1s : W1g;
  int koff = (sec >> 1) * 128;
  Wb[idx] = (unsigned short)f2bf(W[(koff + k) * DHID + n]);
}

// Zq[b][c] = b1g[c] + q[b] @ W1g[256:384]  (fp32, tiny)
__global__ void zq_kernel(const float* __restrict__ q, const float* __restrict__ W1g,
                          const float* __restrict__ b1g, float* __restrict__ Zq) {
  int b = blockIdx.x, c = threadIdx.x;
  float acc = b1g[c];
#pragma unroll 4
  for (int k = 0; k < DH; ++k)
    acc = fmaf(q[b * DH + k], W1g[(2 * DH + k) * DHID + c], acc);
  Zq[b * DHID + c] = acc;
}

// MFMA node projections: D[hid][node] = sum_k Wb[hid][k] * h[node][k].
// Grid: x = node tiles (128), y = 0..7 (128 hid of 1024; sec=y>>1, par=y&1).
// P layout identical to round-2: per node 1024 bf16, section elem for hidden
// col n (0..255): ((n&127)>>2)*8 + (n>>7)*4 + (n&3).
__global__ __launch_bounds__(256)
void node_gemm_mfma(const float* __restrict__ h, const unsigned short* __restrict__ Wb,
                    unsigned short* __restrict__ P) {
  __shared__ unsigned short As[128 * 128];  // [hid][k] chunk-swizzled 32KB
  __shared__ unsigned short Bs[128 * 128];  // [node][k] chunk-swizzled 32KB
  const int tid = threadIdx.x;
  const int lane = tid & 63;
  const int wave = tid >> 6;
  const int node0 = blockIdx.x * 128;
  const int y = blockIdx.y;
  const int hid0 = y * 128;   // row base into Wb (4*256 rows total)

  // stage A: flat copy of Wb rows hid0..+127 (bf16), 16B chunks, XOR swizzle
  {
    const uint4* src = (const uint4*)(Wb + (size_t)hid0 * 128);  // 16 uint4/row
    uint4* dst = (uint4*)As;
#pragma unroll
    for (int it = 0; it < 8; ++it) {
      int c = it * 256 + tid;          // 0..2047
      int r = c >> 4, cc = c & 15;
      dst[r * 16 + (cc ^ (r & 15))] = src[c];
    }
  }
  // stage B: h rows node0..+127 fp32 -> bf16, XOR swizzle
  {
#pragma unroll
    for (int it = 0; it < 16; ++it) {
      int fi = it * 256 + tid;         // float4 idx, 0..4095
      int r = fi >> 5, f4c = fi & 31;
      int n = node0 + r;
      float4 v = make_float4(0.f, 0.f, 0.f, 0.f);
      if (n < NN) v = *(const float4*)&h[(size_t)n * DH + f4c * 4];
      unsigned lo = f2bf(v.x) | (f2bf(v.y) << 16);
      unsigned hi = f2bf(v.z) | (f2bf(v.w) << 16);
      int ch = f4c >> 1, half = f4c & 1;
      *(uint2*)(Bs + r * 128 + ((ch ^ (r & 15)) * 8 + half * 4)) = make_uint2(lo, hi);
    }
  }
  __syncthreads();

  const int r15 = lane & 15, q = lane >> 4;
  const int wm = wave >> 1, wn = wave & 1;   // hid-half, node-half
  f32x4 acc[4][4];
#pragma unroll
  for (int mi = 0; mi < 4; ++mi)
#pragma unroll
    for (int nj = 0; nj < 4; ++nj) acc[mi][nj] = (f32x4)(0.f);

#pragma unroll
  for (int ki = 0; ki < 4; ++ki) {
    bf16x8 a[4], b[4];
    const int sch = (ki * 4 + q);
#pragma unroll
    for (int mi = 0; mi < 4; ++mi) {
      int row = wm * 64 + mi * 16 + r15;
      a[mi] = *(const bf16x8*)(As + row * 128 + (sch ^ r15) * 8);
    }
#pragma unroll
    for (int nj = 0; nj < 4; ++nj) {
      int row = wn * 64 + nj * 16 + r15;
      b[nj] = *(const bf16x8*)(Bs + row * 128 + (sch ^ r15) * 8);
    }
#pragma unroll
    for (int mi = 0; mi < 4; ++mi)
#pragma unroll
      for (int nj = 0; nj < 4; ++nj)
        acc[mi][nj] = __builtin_amdgcn_mfma_f32_16x16x32_bf16(a[mi], b[nj], acc[mi][nj], 0, 0, 0);
  }

  // epilogue: lane regs = 4 consecutive hidden (hs=wm*64+mi*16+q*4+reg) of
  // node (wn*64+nj*16+r15); pack 4 bf16 -> uint2, store in round-2 P layout.
  const int sec = y >> 1, par = y & 1;
#pragma unroll
  for (int mi = 0; mi < 4; ++mi) {
    int slotbase = (wm * 16 + mi * 4 + q) * 8 + par * 4;  // within section
#pragma unroll
    for (int nj = 0; nj < 4; ++nj) {
      int node = node0 + wn * 64 + nj * 16 + r15;
      if (node < NN) {
        f32x4 c = acc[mi][nj];
        unsigned lo = f2bf(c.x) | (f2bf(c.y) << 16);
        unsigned hi = f2bf(c.z) | (f2bf(c.w) << 16);
        *(uint2*)(P + (size_t)node * 1024 + sec * 256 + slotbase) = make_uint2(lo, hi);
      }
    }
  }
}

// Fused edge kernel (unchanged from round 2): se = e@W1s[256:320] fp32 GEMM +
// bf16 gathers + both heads + raw score + segment max.
__global__ __launch_bounds__(256)
void edge_kernel(const float* __restrict__ eattr, const int* __restrict__ eidx,
                 const int* __restrict__ ebat,
                 const float* __restrict__ W1s, const float* __restrict__ b1s,
                 const float* __restrict__ W2g, const float* __restrict__ b2g,
                 const float* __restrict__ W2s, const float* __restrict__ b2s,
                 const unsigned short* __restrict__ P, const float* __restrict__ Zq,
                 float* __restrict__ raw, unsigned* __restrict__ segmax) {
  __shared__ float es[64][64];
  __shared__ float Wc[8][256];
  __shared__ float w2g_s[256], w2s_s[256], b1s_s[256];
  __shared__ int src_s[64], dst_s[64], bat_s[64];
  const int tid = threadIdx.x;
  const int e0 = blockIdx.x * 64;

  {
    int er = tid >> 4;
    int k4 = (tid & 15) * 4;
#pragma unroll
    for (int p = 0; p < 4; ++p) {
      int ee = p * 16 + er;
      *(float4*)&es[ee][k4] = *(const float4*)&eattr[(e0 + ee) * DE + k4];
    }
  }
  w2g_s[tid] = W2g[tid];
  w2s_s[tid] = W2s[tid];
  b1s_s[tid] = b1s[tid];
  if (tid < 64) {
    src_s[tid] = eidx[e0 + tid];
    dst_s[tid] = eidx[NE + e0 + tid];
    bat_s[tid] = ebat[e0 + tid];
  }

  const int cx = tid & 31;
  const int ry = tid >> 5;
  const int r0 = ry * 8;
  float acc[8][8];
#pragma unroll
  for (int i = 0; i < 8; ++i)
#pragma unroll
    for (int j = 0; j < 8; ++j) acc[i][j] = 0.f;

  for (int kc = 0; kc < 8; ++kc) {
    __syncthreads();
    {
      int kk = tid >> 5;
      int cf = (tid & 31) * 8;
      const float* wr = &W1s[(2 * DH + kc * 8 + kk) * DHID + cf];
      *(float4*)&Wc[kk][cf] = *(const float4*)wr;
      *(float4*)&Wc[kk][cf + 4] = *(const float4*)(wr + 4);
    }
    __syncthreads();
    for (int k4 = 0; k4 < 8; k4 += 4) {
      float4 av[8];
#pragma unroll
      for (int i = 0; i < 8; ++i)
        av[i] = *(const float4*)&es[r0 + i][kc * 8 + k4];
#pragma unroll
      for (int kk = 0; kk < 4; ++kk) {
        float4 blo = *(const float4*)&Wc[k4 + kk][cx * 4];
        float4 bhi = *(const float4*)&Wc[k4 + kk][128 + cx * 4];
        float b[8] = {blo.x, blo.y, blo.z, blo.w, bhi.x, bhi.y, bhi.z, bhi.w};
#pragma unroll
        for (int i = 0; i < 8; ++i) {
          const float* ap = (const float*)&av[i];
          float a = ap[kk];
#pragma unroll
          for (int j = 0; j < 8; ++j) acc[i][j] = fmaf(a, b[j], acc[i][j]);
        }
      }
    }
  }

  const uint4* Pq = (const uint4*)P;
  const float4* Zq4 = (const float4*)Zq;
  const float b2gv = b2g[0], b2sv = b2s[0];
  const float4 w2g_lo = *(const float4*)&w2g_s[cx * 4];
  const float4 w2g_hi = *(const float4*)&w2g_s[128 + cx * 4];
  const float4 w2s_lo = *(const float4*)&w2s_s[cx * 4];
  const float4 w2s_hi = *(const float4*)&w2s_s[128 + cx * 4];
  const float4 b1_lo = *(const float4*)&b1s_s[cx * 4];
  const float4 b1_hi = *(const float4*)&b1s_s[128 + cx * 4];
  const float wg[8] = {w2g_lo.x, w2g_lo.y, w2g_lo.z, w2g_lo.w,
                       w2g_hi.x, w2g_hi.y, w2g_hi.z, w2g_hi.w};
  const float ws[8] = {w2s_lo.x, w2s_lo.y, w2s_lo.z, w2s_lo.w,
                       w2s_hi.x, w2s_hi.y, w2s_hi.z, w2s_hi.w};
  const float b1v[8] = {b1_lo.x, b1_lo.y, b1_lo.z, b1_lo.w,
                        b1_hi.x, b1_hi.y, b1_hi.z, b1_hi.w};

  int s_n = src_s[r0], d_n = dst_s[r0], b_n = bat_s[r0];
  uint4 gs_n = Pq[(size_t)s_n * 128 + cx];
  uint4 ss_n = Pq[(size_t)s_n * 128 + 32 + cx];
  uint4 gd_n = Pq[(size_t)d_n * 128 + 64 + cx];
  uint4 sd_n = Pq[(size_t)d_n * 128 + 96 + cx];
  float4 zlo_n = Zq4[b_n * 64 + cx];
  float4 zhi_n = Zq4[b_n * 64 + 32 + cx];

  for (int j = 0; j < 8; ++j) {
    const int dcur = d_n;
    uint4 gs = gs_n, ss = ss_n, gd = gd_n, sd = sd_n;
    float4 zlo = zlo_n, zhi = zhi_n;
    if (j < 7) {
      s_n = src_s[r0 + j + 1]; d_n = dst_s[r0 + j + 1]; b_n = bat_s[r0 + j + 1];
      gs_n = Pq[(size_t)s_n * 128 + cx];
      ss_n = Pq[(size_t)s_n * 128 + 32 + cx];
      gd_n = Pq[(size_t)d_n * 128 + 64 + cx];
      sd_n = Pq[(size_t)d_n * 128 + 96 + cx];
      zlo_n = Zq4[b_n * 64 + cx];
      zhi_n = Zq4[b_n * 64 + 32 + cx];
    }
    float gsf[8], gdf[8], ssf[8], sdf[8];
    bf8_unpack(gs, gsf); bf8_unpack(gd, gdf);
    bf8_unpack(ss, ssf); bf8_unpack(sd, sdf);
    const float zq[8] = {zlo.x, zlo.y, zlo.z, zlo.w, zhi.x, zhi.y, zhi.z, zhi.w};

    float gp = 0.f, sp = 0.f;
#pragma unroll
    for (int t = 0; t < 8; ++t) {
      gp = fmaf(fmaxf(gsf[t] + gdf[t] + zq[t], 0.f), wg[t], gp);
      sp = fmaf(fmaxf(acc[j][t] + ssf[t] + sdf[t] + b1v[t], 0.f), ws[t], sp);
    }
#pragma unroll
    for (int m = 16; m >= 1; m >>= 1) {
      gp += __shfl_xor(gp, m);
      sp += __shfl_xor(sp, m);
    }
    if (cx == 0) {
      float gate = 1.f / (1.f + __expf(-(gp + b2gv)));
      float score = sp + b2sv;
      float rv = gate * score;
      raw[e0 + r0 + j] = rv;
      atomicMax(&segmax[dcur], enc_f(rv));
    }
  }
}

__global__ void exp_pass(const float* __restrict__ raw, const int* __restrict__ dstp,
                         const unsigned* __restrict__ segmax, float* __restrict__ out,
                         float* __restrict__ segsum) {
  int i = blockIdx.x * 256 + threadIdx.x;
  if (i < NE) {
    int d = dstp[i];
    float ex = __expf(raw[i] - dec_f(segmax[d]));
    out[i] = ex;
    atomicAdd(&segsum[d], ex);
  }
}

__global__ void norm_pass(float* __restrict__ out, const int* __restrict__ dstp,
                          const float* __restrict__ segsum) {
  int i = blockIdx.x * 256 + threadIdx.x;
  if (i < NE) out[i] = out[i] / fmaxf(segsum[dstp[i]], 1e-9f);
}

extern "C" void kernel_launch(void* const* d_in, const int* in_sizes, int n_in,
                              void* d_out, int out_size, void* d_ws, size_t ws_size,
                              hipStream_t stream) {
  const float* h   = (const float*)d_in[0];
  const float* e   = (const float*)d_in[1];
  const float* q   = (const float*)d_in[2];
  const int* eidx  = (const int*)d_in[3];
  const int* ebat  = (const int*)d_in[4];
  const float* W1g = (const float*)d_in[5];
  const float* b1g = (const float*)d_in[6];
  const float* W2g = (const float*)d_in[7];
  const float* b2g = (const float*)d_in[8];
  const float* W1s = (const float*)d_in[9];
  const float* b1s = (const float*)d_in[10];
  const float* W2s = (const float*)d_in[11];
  const float* b2s = (const float*)d_in[12];
  float* out = (float*)d_out;

  // workspace carve: P(bf16 102.4MB) | Zq | raw | segmax | segsum | Wb(256KB)
  unsigned short* P = (unsigned short*)d_ws;
  float* Zq = (float*)(P + (size_t)NN * 1024);
  float* raw = Zq + NBATCH * DHID;
  unsigned* segmax = (unsigned*)(raw + NE);
  float* segsum = (float*)(segmax + NN);
  unsigned short* Wb = (unsigned short*)(segsum + NN);

  hipLaunchKernelGGL(init_seg, dim3(196), dim3(256), 0, stream, segmax, segsum);
  hipLaunchKernelGGL(w2bf, dim3(512), dim3(256), 0, stream, W1g, W1s, Wb);
  hipLaunchKernelGGL(zq_kernel, dim3(NBATCH), dim3(256), 0, stream, q, W1g, b1g, Zq);
  hipLaunchKernelGGL(node_gemm_mfma, dim3(391, 8), dim3(256), 0, stream, h, Wb, P);
  hipLaunchKernelGGL(edge_kernel, dim3(NE / 64), dim3(256), 0, stream,
                     e, eidx, ebat, W1s, b1s, W2g, b2g, W2s, b2s, P, Zq, raw, segmax);
  hipLaunchKernelGGL(exp_pass, dim3(1563), dim3(256), 0, stream,
                     raw, eidx + NE, segmax, out, segsum);
  hipLaunchKernelGGL(norm_pass, dim3(1563), dim3(256), 0, stream,
                     out, eidx + NE, segsum);
}

// Round 4
// 525.951 us; speedup vs baseline: 1.9918x; 1.0387x over previous
//
#include <hip/hip_runtime.h>

#define NN 50000
#define NE 400000
#define NBATCH 16
#define DH 128
#define DE 64
#define DHID 256
#define KP 136   // node-kernel LDS row pitch (bf16 elems): 128 + 8 -> 2-way banks
#define EP 72    // edge-kernel LDS row pitch (bf16 elems): 64 + 8  -> 2-way banks

typedef __attribute__((ext_vector_type(8))) short bf16x8;
typedef __attribute__((ext_vector_type(4))) float f32x4;

__device__ __forceinline__ unsigned enc_f(float f) {
  unsigned u = __float_as_uint(f);
  return (u & 0x80000000u) ? ~u : (u | 0x80000000u);
}
__device__ __forceinline__ float dec_f(unsigned x) {
  unsigned u = (x & 0x80000000u) ? (x ^ 0x80000000u) : ~x;
  return __uint_as_float(u);
}
__device__ __forceinline__ unsigned f2bf(float x) {
  unsigned u = __float_as_uint(x);
  return (u + 0x7fffu + ((u >> 16) & 1u)) >> 16;
}
__device__ __forceinline__ void bf8_unpack(uint4 v, float* f) {
  f[0] = __uint_as_float(v.x << 16); f[1] = __uint_as_float(v.x & 0xffff0000u);
  f[2] = __uint_as_float(v.y << 16); f[3] = __uint_as_float(v.y & 0xffff0000u);
  f[4] = __uint_as_float(v.z << 16); f[5] = __uint_as_float(v.z & 0xffff0000u);
  f[6] = __uint_as_float(v.w << 16); f[7] = __uint_as_float(v.w & 0xffff0000u);
}

__global__ void init_seg(unsigned* __restrict__ segmax, float* __restrict__ segsum) {
  int i = blockIdx.x * 256 + threadIdx.x;
  if (i < NN) { segmax[i] = 0u; segsum[i] = 0.0f; }
}

// Wb[1024][128] bf16: row H = sec*256 + hid; sec0=W1g[0:128](gate-src),
// sec1=W1s[0:128](score-src), sec2=W1g[128:256](gate-dst), sec3=W1s[128:256].
// Wbe[256][64] bf16: Wbe[n][k] = W1s[256+k][n] (edge-attr section).
__global__ void w2bf(const float* __restrict__ W1g, const float* __restrict__ W1s,
                     unsigned short* __restrict__ Wb, unsigned short* __restrict__ Wbe) {
  int idx = blockIdx.x * 256 + threadIdx.x;   // 147456 total
  if (idx < 131072) {
    int sec = idx >> 15, rem = idx & 32767, n = rem >> 7, k = rem & 127;
    const float* W = (sec & 1) ? W1s : W1g;
    int koff = (sec >> 1) * 128;
    Wb[idx] = (unsigned short)f2bf(W[(koff + k) * DHID + n]);
  } else {
    int i = idx - 131072;                     // 16384
    int n = i >> 6, k = i & 63;
    Wbe[i] = (unsigned short)f2bf(W1s[(2 * DH + k) * DHID + n]);
  }
}

// Zq permuted fp32: Zq[b*256 + q*64 + t*4 + r] = b1g[hid] + q[b]@W1g[256:384,hid]
// with hid = 16t + 4q + r (matches MFMA C-layout slots).
__global__ void zq_kernel(const float* __restrict__ q, const float* __restrict__ W1g,
                          const float* __restrict__ b1g, float* __restrict__ Zq) {
  int b = blockIdx.x, c = threadIdx.x;   // c = hid
  float acc = b1g[c];
#pragma unroll 4
  for (int k = 0; k < DH; ++k)
    acc = fmaf(q[b * DH + k], W1g[(2 * DH + k) * DHID + c], acc);
  int t = c >> 4, qq = (c >> 2) & 3, r = c & 3;
  Zq[b * 256 + qq * 64 + t * 4 + r] = acc;
}

// Node projections via MFMA. Block = 64 nodes; h staged once (bf16), B-frags
// held in registers; loop 8 chunks of 128 Wb rows (staged from L2-hot Wb).
// P layout: per node 1024 bf16 = 4 sections x 256; slot within section for
// hid = 16t+4q+r is q*64 + t*4 + r.
__global__ __launch_bounds__(256)
void node_gemm(const float* __restrict__ h, const unsigned short* __restrict__ Wb,
               unsigned short* __restrict__ P) {
  __shared__ unsigned short Bs[64 * KP];    // 17408 B  (h tile)
  __shared__ unsigned short As[128 * KP];   // 34816 B  (Wb chunk)
  const int tid = threadIdx.x;
  const int lane = tid & 63, wave = tid >> 6;
  const int node0 = blockIdx.x * 64;

  // stage h rows node0..+63, fp32 -> bf16
#pragma unroll
  for (int it = 0; it < 8; ++it) {
    int fi = it * 256 + tid;            // 2048 float4 = 64 rows x 32
    int row = fi >> 5, f4 = fi & 31;
    int n = node0 + row;
    float4 v = make_float4(0.f, 0.f, 0.f, 0.f);
    if (n < NN) v = *(const float4*)&h[(size_t)n * DH + f4 * 4];
    uint2 pk = make_uint2(f2bf(v.x) | (f2bf(v.y) << 16),
                          f2bf(v.z) | (f2bf(v.w) << 16));
    *(uint2*)(Bs + row * KP + f4 * 4) = pk;
  }
  __syncthreads();

  const int r15 = lane & 15, q = lane >> 4;
  // preload all B fragments (reused across all 8 chunks)
  bf16x8 bfr[4][4];
#pragma unroll
  for (int nj = 0; nj < 4; ++nj)
#pragma unroll
    for (int ki = 0; ki < 4; ++ki)
      bfr[nj][ki] = *(const bf16x8*)(Bs + (nj * 16 + r15) * KP + ki * 32 + q * 8);

  for (int c = 0; c < 8; ++c) {
    __syncthreads();   // previous chunk's readers done
    {
      const uint4* wsrc = (const uint4*)(Wb + (size_t)c * 128 * 128);
#pragma unroll
      for (int it = 0; it < 8; ++it) {
        int i = it * 256 + tid;         // 2048 uint4
        int row = i >> 4, c16 = i & 15;
        *(uint4*)(As + row * KP + c16 * 8) = wsrc[i];
      }
    }
    __syncthreads();
    f32x4 acc[2][4];
#pragma unroll
    for (int mi = 0; mi < 2; ++mi)
#pragma unroll
      for (int nj = 0; nj < 4; ++nj) acc[mi][nj] = (f32x4)(0.f);
#pragma unroll
    for (int ki = 0; ki < 4; ++ki) {
      bf16x8 a0 = *(const bf16x8*)(As + (wave * 32 + r15) * KP + ki * 32 + q * 8);
      bf16x8 a1 = *(const bf16x8*)(As + (wave * 32 + 16 + r15) * KP + ki * 32 + q * 8);
#pragma unroll
      for (int nj = 0; nj < 4; ++nj) {
        acc[0][nj] = __builtin_amdgcn_mfma_f32_16x16x32_bf16(a0, bfr[nj][ki], acc[0][nj], 0, 0, 0);
        acc[1][nj] = __builtin_amdgcn_mfma_f32_16x16x32_bf16(a1, bfr[nj][ki], acc[1][nj], 0, 0, 0);
      }
    }
    // store: sec = c>>1; t = (c&1)*8 + wave*2 + mi; slot = q*64 + t*4 + r
    const int sec = c >> 1;
#pragma unroll
    for (int mi = 0; mi < 2; ++mi) {
      int t = (c & 1) * 8 + wave * 2 + mi;
#pragma unroll
      for (int nj = 0; nj < 4; ++nj) {
        int node = node0 + nj * 16 + r15;
        if (node < NN) {
          f32x4 v = acc[mi][nj];
          uint2 pk = make_uint2(f2bf(v.x) | (f2bf(v.y) << 16),
                                f2bf(v.z) | (f2bf(v.w) << 16));
          *(uint2*)(P + (size_t)node * 1024 + sec * 256 + q * 64 + t * 4) = pk;
        }
      }
    }
  }
}

// Fused edge kernel: score e-GEMM via MFMA (Sc^T: M=hid256, N=edges, K=64),
// permuted bf16 gathers of node projections + both heads + segment max.
__global__ __launch_bounds__(256)
void edge_kernel(const float* __restrict__ eattr, const int* __restrict__ eidx,
                 const int* __restrict__ ebat, const unsigned short* __restrict__ Wbe,
                 const float* __restrict__ b1s,
                 const float* __restrict__ W2g, const float* __restrict__ b2g,
                 const float* __restrict__ W2s, const float* __restrict__ b2s,
                 const unsigned short* __restrict__ P, const float* __restrict__ Zq,
                 float* __restrict__ raw, unsigned* __restrict__ segmax) {
  __shared__ unsigned short Ws[256 * EP];   // 36864 B
  __shared__ unsigned short es[64 * EP];    // 9216 B
  __shared__ float w2g_s[256], w2s_s[256], b1s_s[256];  // permuted
  __shared__ int src_s[64], dst_s[64], bat_s[64];
  const int tid = threadIdx.x;
  const int lane = tid & 63, wave = tid >> 6;
  const int e0 = blockIdx.x * 64;

  {
    const uint4* src = (const uint4*)Wbe;   // 2048 uint4
#pragma unroll
    for (int it = 0; it < 8; ++it) {
      int i = it * 256 + tid;
      int row = i >> 3, c8 = i & 7;
      *(uint4*)(Ws + row * EP + c8 * 8) = src[i];
    }
  }
#pragma unroll
  for (int it = 0; it < 4; ++it) {
    int fi = it * 256 + tid;               // 1024 float4 = 64 rows x 16
    int row = fi >> 4, f4 = fi & 15;
    float4 v = *(const float4*)&eattr[(size_t)(e0 + row) * DE + f4 * 4];
    uint2 pk = make_uint2(f2bf(v.x) | (f2bf(v.y) << 16),
                          f2bf(v.z) | (f2bf(v.w) << 16));
    *(uint2*)(es + row * EP + f4 * 4) = pk;
  }
  {
    int c = tid;                           // slot -> hid = 16t + 4q + r
    int qq = c >> 6, t = (c >> 2) & 15, r = c & 3;
    int hid = t * 16 + qq * 4 + r;
    w2g_s[c] = W2g[hid];
    w2s_s[c] = W2s[hid];
    b1s_s[c] = b1s[hid];
  }
  if (tid < 64) {
    src_s[tid] = eidx[e0 + tid];
    dst_s[tid] = eidx[NE + e0 + tid];
    bat_s[tid] = ebat[e0 + tid];
  }
  __syncthreads();

  const int r15 = lane & 15, q = lane >> 4;
  const int eloc = wave * 16 + r15;        // this lane's edge
  // B fragments (edge attrs), two K-halves
  bf16x8 eb0 = *(const bf16x8*)(es + eloc * EP + q * 8);
  bf16x8 eb1 = *(const bf16x8*)(es + eloc * EP + 32 + q * 8);

  f32x4 acc[16];
#pragma unroll
  for (int t = 0; t < 16; ++t) acc[t] = (f32x4)(0.f);
#pragma unroll
  for (int t = 0; t < 16; ++t) {
    bf16x8 a0 = *(const bf16x8*)(Ws + (t * 16 + r15) * EP + q * 8);
    bf16x8 a1 = *(const bf16x8*)(Ws + (t * 16 + r15) * EP + 32 + q * 8);
    acc[t] = __builtin_amdgcn_mfma_f32_16x16x32_bf16(a0, eb0, acc[t], 0, 0, 0);
    acc[t] = __builtin_amdgcn_mfma_f32_16x16x32_bf16(a1, eb1, acc[t], 0, 0, 0);
  }

  // ---- gather epilogue (per lane: 8 hid per t-pair, depth-1 prefetch) ----
  const uint4* Pq = (const uint4*)P;       // node row = 128 uint4
  const int s = src_s[eloc], d = dst_s[eloc], b = bat_s[eloc];
  const size_t sb = (size_t)s * 128 + q * 8;
  const size_t db = (size_t)d * 128 + q * 8;
  const float* zbase = Zq + b * 256 + q * 64;

  uint4 gi_n = Pq[sb];           // gate-src  (sec0)
  uint4 ss_n = Pq[sb + 32];      // score-src (sec1)
  uint4 gj_n = Pq[db + 64];      // gate-dst  (sec2)
  uint4 sd_n = Pq[db + 96];      // score-dst (sec3)
  float4 zq0_n = *(const float4*)(zbase);
  float4 zq1_n = *(const float4*)(zbase + 4);

  float gp = 0.f, sp = 0.f;
#pragma unroll
  for (int tp = 0; tp < 8; ++tp) {
    uint4 gi = gi_n, ss = ss_n, gj = gj_n, sd = sd_n;
    float4 zq0 = zq0_n, zq1 = zq1_n;
    if (tp < 7) {
      gi_n = Pq[sb + tp + 1];
      ss_n = Pq[sb + 32 + tp + 1];
      gj_n = Pq[db + 64 + tp + 1];
      sd_n = Pq[db + 96 + tp + 1];
      zq0_n = *(const float4*)(zbase + tp * 8 + 8);
      zq1_n = *(const float4*)(zbase + tp * 8 + 12);
    }
    const int so = q * 64 + tp * 8;
    float4 wg0 = *(const float4*)&w2g_s[so], wg1 = *(const float4*)&w2g_s[so + 4];
    float4 ws0 = *(const float4*)&w2s_s[so], ws1 = *(const float4*)&w2s_s[so + 4];
    float4 bs0 = *(const float4*)&b1s_s[so], bs1 = *(const float4*)&b1s_s[so + 4];
    float gif[8], gjf[8], ssf[8], sdf[8];
    bf8_unpack(gi, gif); bf8_unpack(gj, gjf);
    bf8_unpack(ss, ssf); bf8_unpack(sd, sdf);
    const float zq[8] = {zq0.x, zq0.y, zq0.z, zq0.w, zq1.x, zq1.y, zq1.z, zq1.w};
    const float wg[8] = {wg0.x, wg0.y, wg0.z, wg0.w, wg1.x, wg1.y, wg1.z, wg1.w};
    const float wsv[8] = {ws0.x, ws0.y, ws0.z, ws0.w, ws1.x, ws1.y, ws1.z, ws1.w};
    const float bsv[8] = {bs0.x, bs0.y, bs0.z, bs0.w, bs1.x, bs1.y, bs1.z, bs1.w};
    const f32x4 alo = acc[2 * tp], ahi = acc[2 * tp + 1];
    const float av[8] = {alo.x, alo.y, alo.z, alo.w, ahi.x, ahi.y, ahi.z, ahi.w};
#pragma unroll
    for (int i = 0; i < 8; ++i) {
      gp = fmaf(fmaxf(gif[i] + gjf[i] + zq[i], 0.f), wg[i], gp);
      sp = fmaf(fmaxf(av[i] + ssf[i] + sdf[i] + bsv[i], 0.f), wsv[i], sp);
    }
  }
  gp += __shfl_xor(gp, 16); gp += __shfl_xor(gp, 32);
  sp += __shfl_xor(sp, 16); sp += __shfl_xor(sp, 32);
  if (q == 0) {
    float gate = 1.f / (1.f + __expf(-(gp + b2g[0])));
    float rv = gate * (sp + b2s[0]);
    raw[e0 + eloc] = rv;
    atomicMax(&segmax[d], enc_f(rv));
  }
}

__global__ void exp_pass(const float* __restrict__ raw, const int* __restrict__ dstp,
                         const unsigned* __restrict__ segmax, float* __restrict__ out,
                         float* __restrict__ segsum) {
  int i = blockIdx.x * 256 + threadIdx.x;
  if (i < NE) {
    int d = dstp[i];
    float ex = __expf(raw[i] - dec_f(segmax[d]));
    out[i] = ex;
    atomicAdd(&segsum[d], ex);
  }
}

__global__ void norm_pass(float* __restrict__ out, const int* __restrict__ dstp,
                          const float* __restrict__ segsum) {
  int i = blockIdx.x * 256 + threadIdx.x;
  if (i < NE) out[i] = out[i] / fmaxf(segsum[dstp[i]], 1e-9f);
}

extern "C" void kernel_launch(void* const* d_in, const int* in_sizes, int n_in,
                              void* d_out, int out_size, void* d_ws, size_t ws_size,
                              hipStream_t stream) {
  const float* h   = (const float*)d_in[0];
  const float* e   = (const float*)d_in[1];
  const float* q   = (const float*)d_in[2];
  const int* eidx  = (const int*)d_in[3];
  const int* ebat  = (const int*)d_in[4];
  const float* W1g = (const float*)d_in[5];
  const float* b1g = (const float*)d_in[6];
  const float* W2g = (const float*)d_in[7];
  const float* b2g = (const float*)d_in[8];
  const float* W1s = (const float*)d_in[9];
  const float* b1s = (const float*)d_in[10];
  const float* W2s = (const float*)d_in[11];
  const float* b2s = (const float*)d_in[12];
  float* out = (float*)d_out;

  // ws carve: P(bf16 102.4MB) | Zq(16KB) | raw | segmax | segsum | Wb | Wbe
  unsigned short* P = (unsigned short*)d_ws;
  float* Zq = (float*)(P + (size_t)NN * 1024);
  float* raw = Zq + NBATCH * DHID;
  unsigned* segmax = (unsigned*)(raw + NE);
  float* segsum = (float*)(segmax + NN);
  unsigned short* Wb = (unsigned short*)(segsum + NN);
  unsigned short* Wbe = Wb + 131072;

  hipLaunchKernelGGL(init_seg, dim3(196), dim3(256), 0, stream, segmax, segsum);
  hipLaunchKernelGGL(w2bf, dim3(576), dim3(256), 0, stream, W1g, W1s, Wb, Wbe);
  hipLaunchKernelGGL(zq_kernel, dim3(NBATCH), dim3(256), 0, stream, q, W1g, b1g, Zq);
  hipLaunchKernelGGL(node_gemm, dim3(782), dim3(256), 0, stream, h, Wb, P);
  hipLaunchKernelGGL(edge_kernel, dim3(NE / 64), dim3(256), 0, stream,
                     e, eidx, ebat, Wbe, b1s, W2g, b2g, W2s, b2s, P, Zq, raw, segmax);
  hipLaunchKernelGGL(exp_pass, dim3(1563), dim3(256), 0, stream,
                     raw, eidx + NE, segmax, out, segsum);
  hipLaunchKernelGGL(norm_pass, dim3(1563), dim3(256), 0, stream,
                     out, eidx + NE, segsum);
}

// Round 5
// 451.455 us; speedup vs baseline: 2.3205x; 1.1650x over previous
//
#include <hip/hip_runtime.h>

#define NN 50000
#define NE 400000
#define NBATCH 16
#define DH 128
#define DE 64
#define DHID 256
#define EP 72    // edge-kernel LDS row pitch (bf16): 64 + 8
#define SCP 258  // Sc LDS row pitch (bf16): 256 + 2 -> 4-way max on writes

typedef __attribute__((ext_vector_type(8))) short bf16x8;
typedef __attribute__((ext_vector_type(4))) float f32x4;

__device__ __forceinline__ unsigned enc_f(float f) {
  unsigned u = __float_as_uint(f);
  return (u & 0x80000000u) ? ~u : (u | 0x80000000u);
}
__device__ __forceinline__ float dec_f(unsigned x) {
  unsigned u = (x & 0x80000000u) ? (x ^ 0x80000000u) : ~x;
  return __uint_as_float(u);
}
__device__ __forceinline__ unsigned f2bf(float x) {
  unsigned u = __float_as_uint(x);
  return (u + 0x7fffu + ((u >> 16) & 1u)) >> 16;
}
__device__ __forceinline__ void bf8_unpack(uint4 v, float* f) {
  f[0] = __uint_as_float(v.x << 16); f[1] = __uint_as_float(v.x & 0xffff0000u);
  f[2] = __uint_as_float(v.y << 16); f[3] = __uint_as_float(v.y & 0xffff0000u);
  f[4] = __uint_as_float(v.z << 16); f[5] = __uint_as_float(v.z & 0xffff0000u);
  f[6] = __uint_as_float(v.w << 16); f[7] = __uint_as_float(v.w & 0xffff0000u);
}

__global__ void init_seg(unsigned* __restrict__ segmax, float* __restrict__ segsum) {
  int i = blockIdx.x * 256 + threadIdx.x;
  if (i < NN) { segmax[i] = 0u; segsum[i] = 0.0f; }
}

// WbS: 4 sections x 32768 bf16, PRE-SWIZZLED so a linear LDS copy yields the
// XOR-chunk layout: within section, uint4 slot i4 = row*16 + (c16 ^ (row&15))
// holds W[koff + c16*8 + comp][row] (row = hid 0..255, k = c16*8+comp).
// Wbe[256][64]: Wbe[n][k] = W1s[256+k][n].
__global__ void w2bf(const float* __restrict__ W1g, const float* __restrict__ W1s,
                     unsigned short* __restrict__ WbS, unsigned short* __restrict__ Wbe) {
  int idx = blockIdx.x * 256 + threadIdx.x;   // 147456 total
  if (idx < 131072) {
    int sec = idx >> 15, el = idx & 32767;
    int i4 = el >> 3, comp = el & 7;
    int row = i4 >> 4, swz = i4 & 15;
    int c16 = swz ^ (row & 15);
    int k = c16 * 8 + comp;
    const float* W = (sec & 1) ? W1s : W1g;
    int koff = (sec >> 1) * 128;
    WbS[idx] = (unsigned short)f2bf(W[(koff + k) * DHID + row]);
  } else {
    int i = idx - 131072;
    int n = i >> 6, k = i & 63;
    Wbe[i] = (unsigned short)f2bf(W1s[(2 * DH + k) * DHID + n]);
  }
}

// Zq permuted fp32: Zq[b*256 + slot], slot = q*64 + t*4 + r, hid = 16t+4q+r.
__global__ void zq_kernel(const float* __restrict__ q, const float* __restrict__ W1g,
                          const float* __restrict__ b1g, float* __restrict__ Zq) {
  int b = blockIdx.x, c = threadIdx.x;   // c = hid
  float acc = b1g[c];
#pragma unroll 4
  for (int k = 0; k < DH; ++k)
    acc = fmaf(q[b * DH + k], W1g[(2 * DH + k) * DHID + c], acc);
  int t = c >> 4, qq = (c >> 2) & 3, r = c & 3;
  Zq[b * 256 + qq * 64 + t * 4 + r] = acc;
}

// Node projections: block = 128 nodes x 1 section (256 hid), K=128.
// One-shot staging (no inner barriers): As = whole pre-swizzled W section
// (64KB, linear copy), Bs = h tile fp32->bf16 XOR-swizzled (32KB).
// P: per node 1024 bf16 = 4 sections x 256 slots; slot = q*64 + t*4 + r.
__global__ __launch_bounds__(256, 1)
void node_gemm(const float* __restrict__ h, const unsigned short* __restrict__ WbS,
               unsigned short* __restrict__ P) {
  __shared__ unsigned short As[256 * 128];  // 64KB
  __shared__ unsigned short Bs[128 * 128];  // 32KB
  const int tid = threadIdx.x;
  const int lane = tid & 63, wave = tid >> 6;
  const int node0 = blockIdx.x * 128;
  const int sec = blockIdx.y;

  {  // stage A: linear 4096-uint4 copy (source pre-swizzled)
    const uint4* src = (const uint4*)(WbS + (size_t)sec * 32768);
    uint4* dst = (uint4*)As;
#pragma unroll
    for (int it = 0; it < 16; ++it)
      dst[it * 256 + tid] = src[it * 256 + tid];
  }
#pragma unroll
  for (int it = 0; it < 16; ++it) {   // stage B: 4096 float4 = 128 rows x 32
    int fi = it * 256 + tid;
    int row = fi >> 5, f4 = fi & 31;
    int n = node0 + row;
    float4 v = make_float4(0.f, 0.f, 0.f, 0.f);
    if (n < NN) v = *(const float4*)&h[(size_t)n * DH + f4 * 4];
    uint2 pk = make_uint2(f2bf(v.x) | (f2bf(v.y) << 16),
                          f2bf(v.z) | (f2bf(v.w) << 16));
    int ch = f4 >> 1, half = f4 & 1;
    *(uint2*)(Bs + row * 128 + ((ch ^ (row & 15)) * 8 + half * 4)) = pk;
  }
  __syncthreads();

  const int r15 = lane & 15, q = lane >> 4;
  f32x4 acc[4][8];
#pragma unroll
  for (int mi = 0; mi < 4; ++mi)
#pragma unroll
    for (int nj = 0; nj < 8; ++nj) acc[mi][nj] = (f32x4)(0.f);

#pragma unroll
  for (int ki = 0; ki < 4; ++ki) {
    const int c16 = ki * 4 + q;
    bf16x8 b[8];
#pragma unroll
    for (int nj = 0; nj < 8; ++nj)
      b[nj] = *(const bf16x8*)(Bs + (nj * 16 + r15) * 128 + ((c16 ^ r15) * 8));
#pragma unroll
    for (int mi = 0; mi < 4; ++mi) {
      int hr = wave * 64 + mi * 16 + r15;        // hr & 15 == r15
      bf16x8 a = *(const bf16x8*)(As + (hr * 16 + (c16 ^ r15)) * 8);
#pragma unroll
      for (int nj = 0; nj < 8; ++nj)
        acc[mi][nj] = __builtin_amdgcn_mfma_f32_16x16x32_bf16(a, b[nj], acc[mi][nj], 0, 0, 0);
    }
  }
#pragma unroll
  for (int mi = 0; mi < 4; ++mi) {
    int t = wave * 4 + mi;
#pragma unroll
    for (int nj = 0; nj < 8; ++nj) {
      int node = node0 + nj * 16 + r15;
      if (node < NN) {
        f32x4 v = acc[mi][nj];
        uint2 pk = make_uint2(f2bf(v.x) | (f2bf(v.y) << 16),
                              f2bf(v.z) | (f2bf(v.w) << 16));
        *(uint2*)(P + (size_t)node * 1024 + sec * 256 + q * 64 + t * 4) = pk;
      }
    }
  }
}

// Fused edge kernel: MFMA e-GEMM -> Sc via LDS round-trip -> fully-coalesced
// gather epilogue (2 edges x 32 lanes per wave per round).
__global__ __launch_bounds__(256)
void edge_kernel(const float* __restrict__ eattr, const int* __restrict__ eidx,
                 const int* __restrict__ ebat, const unsigned short* __restrict__ Wbe,
                 const float* __restrict__ b1s,
                 const float* __restrict__ W2g, const float* __restrict__ b2g,
                 const float* __restrict__ W2s, const float* __restrict__ b2s,
                 const unsigned short* __restrict__ P, const float* __restrict__ Zq,
                 float* __restrict__ raw, unsigned* __restrict__ segmax) {
  __shared__ unsigned short Ws[256 * EP];   // 36864B; aliased as Sc after GEMM
  __shared__ unsigned short es[64 * EP];    // 9216B
  __shared__ float w2g_s[256], w2s_s[256], b1s_s[256];  // slot-permuted
  __shared__ int src_s[64], dst_s[64], bat_s[64];
  const int tid = threadIdx.x;
  const int lane = tid & 63, wave = tid >> 6;
  const int e0 = blockIdx.x * 64;

  {
    const uint4* src = (const uint4*)Wbe;   // 2048 uint4
#pragma unroll
    for (int it = 0; it < 8; ++it) {
      int i = it * 256 + tid;
      int row = i >> 3, c8 = i & 7;
      *(uint4*)(Ws + row * EP + c8 * 8) = src[i];
    }
  }
#pragma unroll
  for (int it = 0; it < 4; ++it) {
    int fi = it * 256 + tid;               // 1024 float4 = 64 rows x 16
    int row = fi >> 4, f4 = fi & 15;
    float4 v = *(const float4*)&eattr[(size_t)(e0 + row) * DE + f4 * 4];
    uint2 pk = make_uint2(f2bf(v.x) | (f2bf(v.y) << 16),
                          f2bf(v.z) | (f2bf(v.w) << 16));
    *(uint2*)(es + row * EP + f4 * 4) = pk;
  }
  {
    int c = tid;                           // slot -> hid = 16t + 4q + r
    int qq = c >> 6, t = (c >> 2) & 15, r = c & 3;
    int hid = t * 16 + qq * 4 + r;
    w2g_s[c] = W2g[hid];
    w2s_s[c] = W2s[hid];
    b1s_s[c] = b1s[hid];
  }
  if (tid < 64) {
    src_s[tid] = eidx[e0 + tid];
    dst_s[tid] = eidx[NE + e0 + tid];
    bat_s[tid] = ebat[e0 + tid];
  }
  __syncthreads();

  const int r15 = lane & 15, q = lane >> 4;
  const int eloc = wave * 16 + r15;
  bf16x8 eb0 = *(const bf16x8*)(es + eloc * EP + q * 8);
  bf16x8 eb1 = *(const bf16x8*)(es + eloc * EP + 32 + q * 8);

  f32x4 acc[16];
#pragma unroll
  for (int t = 0; t < 16; ++t) acc[t] = (f32x4)(0.f);
#pragma unroll
  for (int t = 0; t < 16; ++t) {
    bf16x8 a0 = *(const bf16x8*)(Ws + (t * 16 + r15) * EP + q * 8);
    bf16x8 a1 = *(const bf16x8*)(Ws + (t * 16 + r15) * EP + 32 + q * 8);
    acc[t] = __builtin_amdgcn_mfma_f32_16x16x32_bf16(a0, eb0, acc[t], 0, 0, 0);
    acc[t] = __builtin_amdgcn_mfma_f32_16x16x32_bf16(a1, eb1, acc[t], 0, 0, 0);
  }

  __syncthreads();                 // all Ws reads done; safe to alias
  unsigned short* Sc = Ws;         // [64][SCP] bf16, slot order
#pragma unroll
  for (int t = 0; t < 16; ++t) {
    f32x4 v = acc[t];
    uint2 pk = make_uint2(f2bf(v.x) | (f2bf(v.y) << 16),
                          f2bf(v.z) | (f2bf(v.w) << 16));
    *(uint2*)(Sc + eloc * SCP + q * 64 + t * 4) = pk;
  }
  __syncthreads();

  // ---- coalesced gather epilogue: 2 edges/wave/round, 8 rounds ----
  const uint4* Pq = (const uint4*)P;   // node row = 128 uint4
  const int cx = lane & 31, eh = lane >> 5;
  const float b2gv = b2g[0], b2sv = b2s[0];
  const int so = cx * 8;
  float4 wg0 = *(const float4*)&w2g_s[so], wg1 = *(const float4*)&w2g_s[so + 4];
  float4 ws0 = *(const float4*)&w2s_s[so], ws1 = *(const float4*)&w2s_s[so + 4];
  float4 bs0 = *(const float4*)&b1s_s[so], bs1 = *(const float4*)&b1s_s[so + 4];
  const float wg[8] = {wg0.x, wg0.y, wg0.z, wg0.w, wg1.x, wg1.y, wg1.z, wg1.w};
  const float wsv[8] = {ws0.x, ws0.y, ws0.z, ws0.w, ws1.x, ws1.y, ws1.z, ws1.w};
  const float bsv[8] = {bs0.x, bs0.y, bs0.z, bs0.w, bs1.x, bs1.y, bs1.z, bs1.w};

  int er = wave * 16 + eh;
  int s = src_s[er], d = dst_s[er], b = bat_s[er];
  uint4 gi_n = Pq[(size_t)s * 128 + cx];
  uint4 ss_n = Pq[(size_t)s * 128 + 32 + cx];
  uint4 gj_n = Pq[(size_t)d * 128 + 64 + cx];
  uint4 sd_n = Pq[(size_t)d * 128 + 96 + cx];

  for (int rr = 0; rr < 8; ++rr) {
    uint4 gi = gi_n, ss = ss_n, gj = gj_n, sd = sd_n;
    const int ercur = er, dcur = d, bcur = b;
    if (rr < 7) {
      er = wave * 16 + (rr + 1) * 2 + eh;
      s = src_s[er]; d = dst_s[er]; b = bat_s[er];
      gi_n = Pq[(size_t)s * 128 + cx];
      ss_n = Pq[(size_t)s * 128 + 32 + cx];
      gj_n = Pq[(size_t)d * 128 + 64 + cx];
      sd_n = Pq[(size_t)d * 128 + 96 + cx];
    }
    uint4 sc = *(const uint4*)(Sc + ercur * SCP + so);
    float4 z0 = *(const float4*)&Zq[bcur * 256 + so];
    float4 z1 = *(const float4*)&Zq[bcur * 256 + so + 4];
    float gif[8], gjf[8], ssf[8], sdf[8], scf[8];
    bf8_unpack(gi, gif); bf8_unpack(gj, gjf);
    bf8_unpack(ss, ssf); bf8_unpack(sd, sdf);
    bf8_unpack(sc, scf);
    const float zq[8] = {z0.x, z0.y, z0.z, z0.w, z1.x, z1.y, z1.z, z1.w};
    float gp = 0.f, sp = 0.f;
#pragma unroll
    for (int i = 0; i < 8; ++i) {
      gp = fmaf(fmaxf(gif[i] + gjf[i] + zq[i], 0.f), wg[i], gp);
      sp = fmaf(fmaxf(scf[i] + ssf[i] + sdf[i] + bsv[i], 0.f), wsv[i], sp);
    }
#pragma unroll
    for (int m = 16; m >= 1; m >>= 1) {   // reduce within 32-lane half
      gp += __shfl_xor(gp, m);
      sp += __shfl_xor(sp, m);
    }
    if (cx == 0) {
      float gate = 1.f / (1.f + __expf(-(gp + b2gv)));
      float rv = gate * (sp + b2sv);
      raw[e0 + ercur] = rv;
      atomicMax(&segmax[dcur], enc_f(rv));
    }
  }
}

__global__ void exp_pass(const float* __restrict__ raw, const int* __restrict__ dstp,
                         const unsigned* __restrict__ segmax, float* __restrict__ out,
                         float* __restrict__ segsum) {
  int i = blockIdx.x * 256 + threadIdx.x;
  if (i < NE) {
    int d = dstp[i];
    float ex = __expf(raw[i] - dec_f(segmax[d]));
    out[i] = ex;
    atomicAdd(&segsum[d], ex);
  }
}

__global__ void norm_pass(float* __restrict__ out, const int* __restrict__ dstp,
                          const float* __restrict__ segsum) {
  int i = blockIdx.x * 256 + threadIdx.x;
  if (i < NE) out[i] = out[i] / fmaxf(segsum[dstp[i]], 1e-9f);
}

extern "C" void kernel_launch(void* const* d_in, const int* in_sizes, int n_in,
                              void* d_out, int out_size, void* d_ws, size_t ws_size,
                              hipStream_t stream) {
  const float* h   = (const float*)d_in[0];
  const float* e   = (const float*)d_in[1];
  const float* q   = (const float*)d_in[2];
  const int* eidx  = (const int*)d_in[3];
  const int* ebat  = (const int*)d_in[4];
  const float* W1g = (const float*)d_in[5];
  const float* b1g = (const float*)d_in[6];
  const float* W2g = (const float*)d_in[7];
  const float* b2g = (const float*)d_in[8];
  const float* W1s = (const float*)d_in[9];
  const float* b1s = (const float*)d_in[10];
  const float* W2s = (const float*)d_in[11];
  const float* b2s = (const float*)d_in[12];
  float* out = (float*)d_out;

  // ws carve: P(bf16 102.4MB) | Zq(16KB) | raw | segmax | segsum | WbS | Wbe
  unsigned short* P = (unsigned short*)d_ws;
  float* Zq = (float*)(P + (size_t)NN * 1024);
  float* raw = Zq + NBATCH * DHID;
  unsigned* segmax = (unsigned*)(raw + NE);
  float* segsum = (float*)(segmax + NN);
  unsigned short* WbS = (unsigned short*)(segsum + NN);
  unsigned short* Wbe = WbS + 131072;

  hipLaunchKernelGGL(init_seg, dim3(196), dim3(256), 0, stream, segmax, segsum);
  hipLaunchKernelGGL(w2bf, dim3(576), dim3(256), 0, stream, W1g, W1s, WbS, Wbe);
  hipLaunchKernelGGL(zq_kernel, dim3(NBATCH), dim3(256), 0, stream, q, W1g, b1g, Zq);
  hipLaunchKernelGGL(node_gemm, dim3(391, 4), dim3(256), 0, stream, h, WbS, P);
  hipLaunchKernelGGL(edge_kernel, dim3(NE / 64), dim3(256), 0, stream,
                     e, eidx, ebat, Wbe, b1s, W2g, b2g, W2s, b2s, P, Zq, raw, segmax);
  hipLaunchKernelGGL(exp_pass, dim3(1563), dim3(256), 0, stream,
                     raw, eidx + NE, segmax, out, segsum);
  hipLaunchKernelGGL(norm_pass, dim3(1563), dim3(256), 0, stream,
                     out, eidx + NE, segsum);
}